// Round 1
// baseline (584.226 us; speedup 1.0000x reference)
//
#include <hip/hip_runtime.h>

// Problem constants
#define B_  4
#define S_  2048
#define E_  1024
#define H_  16
#define DK_ 64
#define M_  (B_*S_)   // 8192

typedef __attribute__((ext_vector_type(8))) short short8;   // 8 bf16 (4 VGPRs)
typedef __attribute__((ext_vector_type(4))) float f32x4;    // MFMA accumulator

// fp32 -> bf16 round-to-nearest-even
__device__ __forceinline__ unsigned short f2b(float f) {
    union { float f; unsigned u; } v; v.f = f;
    unsigned u = v.u;
    return (unsigned short)((u + 0x7fffu + ((u >> 16) & 1u)) >> 16);
}

__global__ __launch_bounds__(256) void cvt_bf16(const float* __restrict__ src,
                                                unsigned short* __restrict__ dst, int n4) {
    int i = blockIdx.x * 256 + threadIdx.x;
    if (i < n4) {
        float4 f = ((const float4*)src)[i];
        ushort4 o;
        o.x = f2b(f.x); o.y = f2b(f.y); o.z = f2b(f.z); o.w = f2b(f.w);
        ((ushort4*)dst)[i] = o;
    }
}

// y = x @ W_z.T ; q/k = cos(y + theta) -> [bh][s][d] ; v -> cos -> transposed [bh][d][s]
__global__ __launch_bounds__(256) void gemm_qkv(
    const unsigned short* __restrict__ xb,   // [M][E] bf16
    const unsigned short* __restrict__ Wb,   // [3][E][E] bf16 (rows = output n, cols = k)
    const float* __restrict__ theta,         // [64] fp32
    unsigned short* __restrict__ qb,         // [B*H][S][DK]
    unsigned short* __restrict__ kb,         // [B*H][S][DK]
    unsigned short* __restrict__ vtb)        // [B*H][DK][S]
{
    __shared__ unsigned short As[64*64];
    __shared__ unsigned short Bs[64*64];
    const int tid = threadIdx.x;
    const int w = tid >> 6, lane = tid & 63, quad = lane >> 4, col = lane & 15;
    const int m0 = blockIdx.x * 64, n0 = blockIdx.y * 64, z = blockIdx.z;
    const unsigned short* Wz = Wb + (size_t)z * E_ * E_;

    f32x4 acc[4] = {};
    for (int k0 = 0; k0 < E_; k0 += 64) {
        for (int i = tid; i < 512; i += 256) {           // 64 rows x 8 chunks of 8 bf16
            int row = i >> 3, c8 = (i & 7) * 8;
            *(int4*)&As[row*64 + c8] = *(const int4*)&xb[(size_t)(m0+row)*E_ + k0 + c8];
            *(int4*)&Bs[row*64 + c8] = *(const int4*)&Wz[(size_t)(n0+row)*E_ + k0 + c8];
        }
        __syncthreads();
        #pragma unroll
        for (int kk = 0; kk < 64; kk += 32) {
            // A-frag: A[m=lane&15][k=quad*8+j]
            short8 a = *(const short8*)&As[(w*16 + col)*64 + kk + quad*8];
            #pragma unroll
            for (int nt = 0; nt < 4; nt++) {
                // B^T-frag: W[n=lane&15][k=quad*8+j]
                short8 b = *(const short8*)&Bs[(nt*16 + col)*64 + kk + quad*8];
                acc[nt] = __builtin_amdgcn_mfma_f32_16x16x32_bf16(a, b, acc[nt], 0, 0, 0);
            }
        }
        __syncthreads();
    }
    // Epilogue: C/D layout col=lane&15, row=quad*4+reg
    #pragma unroll
    for (int nt = 0; nt < 4; nt++) {
        int n = n0 + nt*16 + col;
        int h = n >> 6, d = n & 63;
        float th = theta[d];
        #pragma unroll
        for (int r = 0; r < 4; r++) {
            int m = m0 + w*16 + quad*4 + r;
            int b = m >> 11, s = m & (S_-1);
            unsigned short o = f2b(__cosf(acc[nt][r] + th));
            int bh = b*H_ + h;
            if (z == 0)      qb [((size_t)bh*S_ + s)*DK_ + d] = o;
            else if (z == 1) kb [((size_t)bh*S_ + s)*DK_ + d] = o;
            else             vtb[((size_t)bh*DK_ + d)*S_ + s] = o;
        }
    }
}

// Flash attention: one block = 64 query rows of one head; 4 waves x 16 rows.
__global__ __launch_bounds__(256) void flash_attn(
    const unsigned short* __restrict__ qb,
    const unsigned short* __restrict__ kb,
    const unsigned short* __restrict__ vtb,
    unsigned short* __restrict__ ctx)        // [M][E] bf16
{
    __shared__ unsigned short Kt[64*64];     // [key][d]
    __shared__ unsigned short Vt[64*64];     // [d][key]  (V pre-transposed in global)
    __shared__ unsigned short Pl[4][16*64];  // per-wave P staging [q][key]
    const int tid = threadIdx.x;
    const int w = tid >> 6, lane = tid & 63, quad = lane >> 4, col = lane & 15;
    const int q0 = blockIdx.x * 64;
    const int bh = blockIdx.y;

    // Q fragments, kept in registers for the whole loop (A-layout)
    short8 qf[2];
    {
        const unsigned short* qrow = qb + ((size_t)bh*S_ + q0 + w*16 + col)*DK_;
        qf[0] = *(const short8*)&qrow[quad*8];
        qf[1] = *(const short8*)&qrow[32 + quad*8];
    }

    float m_r[4] = {-1e30f, -1e30f, -1e30f, -1e30f};
    float l_r[4] = {0.f, 0.f, 0.f, 0.f};
    f32x4 o_acc[4] = {};

    for (int kt = 0; kt < S_; kt += 64) {
        __syncthreads();   // protect LDS tiles from previous iteration's readers
        for (int i = tid; i < 512; i += 256) {
            int row = i >> 3, c8 = (i & 7) * 8;
            *(int4*)&Kt[row*64 + c8] = *(const int4*)&kb [((size_t)bh*S_  + kt + row)*DK_ + c8];
            *(int4*)&Vt[row*64 + c8] = *(const int4*)&vtb[((size_t)bh*DK_ + row)*S_ + kt + c8];
        }
        __syncthreads();

        // scores: S[q][key] = sum_d Q[q][d] K[key][d], scaled by 1/sqrt(64)
        f32x4 sacc[4] = {};
        #pragma unroll
        for (int kk = 0; kk < 2; kk++) {
            #pragma unroll
            for (int ct = 0; ct < 4; ct++) {
                short8 bf = *(const short8*)&Kt[(ct*16 + col)*64 + kk*32 + quad*8];
                sacc[ct] = __builtin_amdgcn_mfma_f32_16x16x32_bf16(qf[kk], bf, sacc[ct], 0, 0, 0);
            }
        }
        #pragma unroll
        for (int ct = 0; ct < 4; ct++)
            #pragma unroll
            for (int r = 0; r < 4; r++)
                sacc[ct][r] *= 0.125f;

        // online softmax; rows live at row=quad*4+r, cols across 16 lanes of the quad
        float alpha[4];
        #pragma unroll
        for (int r = 0; r < 4; r++) {
            float t = fmaxf(fmaxf(sacc[0][r], sacc[1][r]), fmaxf(sacc[2][r], sacc[3][r]));
            #pragma unroll
            for (int off = 8; off >= 1; off >>= 1)
                t = fmaxf(t, __shfl_xor(t, off, 16));
            float mn = fmaxf(m_r[r], t);
            alpha[r] = __expf(m_r[r] - mn);
            m_r[r] = mn;
        }
        float rsum[4] = {0.f, 0.f, 0.f, 0.f};
        #pragma unroll
        for (int ct = 0; ct < 4; ct++) {
            #pragma unroll
            for (int r = 0; r < 4; r++) {
                float p = __expf(sacc[ct][r] - m_r[r]);
                rsum[r] += p;
                Pl[w][(quad*4 + r)*64 + ct*16 + col] = f2b(p);  // C-layout -> [q][key]
            }
        }
        #pragma unroll
        for (int r = 0; r < 4; r++) {
            float t = rsum[r];
            #pragma unroll
            for (int off = 8; off >= 1; off >>= 1)
                t += __shfl_xor(t, off, 16);
            l_r[r] = l_r[r] * alpha[r] + t;
        }
        #pragma unroll
        for (int dt = 0; dt < 4; dt++)
            #pragma unroll
            for (int r = 0; r < 4; r++)
                o_acc[dt][r] *= alpha[r];

        // PV: O[q][d] += sum_key P[q][key] V[key][d]
        #pragma unroll
        for (int kk = 0; kk < 2; kk++) {
            short8 pa = *(const short8*)&Pl[w][col*64 + kk*32 + quad*8];   // A-layout read-back
            #pragma unroll
            for (int dt = 0; dt < 4; dt++) {
                short8 bv = *(const short8*)&Vt[(dt*16 + col)*64 + kk*32 + quad*8];
                o_acc[dt] = __builtin_amdgcn_mfma_f32_16x16x32_bf16(pa, bv, o_acc[dt], 0, 0, 0);
            }
        }
    }

    // epilogue: normalize, write ctx [b*S+s][h*64+d]
    const int b = bh >> 4, h = bh & 15;
    #pragma unroll
    for (int r = 0; r < 4; r++) {
        float inv = 1.0f / l_r[r];
        int s = q0 + w*16 + quad*4 + r;
        size_t rowoff = ((size_t)(b*S_ + s))*E_ + h*64;
        #pragma unroll
        for (int dt = 0; dt < 4; dt++)
            ctx[rowoff + dt*16 + col] = f2b(o_acc[dt][r] * inv);
    }
}

// out = ctx @ Wo.T, fp32 output
__global__ __launch_bounds__(256) void gemm_out(
    const unsigned short* __restrict__ ctx,  // [M][E] bf16
    const unsigned short* __restrict__ Wob,  // [E][E] bf16
    float* __restrict__ out)                 // [M][E] fp32
{
    __shared__ unsigned short As[64*64];
    __shared__ unsigned short Bs[64*64];
    const int tid = threadIdx.x;
    const int w = tid >> 6, lane = tid & 63, quad = lane >> 4, col = lane & 15;
    const int m0 = blockIdx.x * 64, n0 = blockIdx.y * 64;

    f32x4 acc[4] = {};
    for (int k0 = 0; k0 < E_; k0 += 64) {
        for (int i = tid; i < 512; i += 256) {
            int row = i >> 3, c8 = (i & 7) * 8;
            *(int4*)&As[row*64 + c8] = *(const int4*)&ctx[(size_t)(m0+row)*E_ + k0 + c8];
            *(int4*)&Bs[row*64 + c8] = *(const int4*)&Wob[(size_t)(n0+row)*E_ + k0 + c8];
        }
        __syncthreads();
        #pragma unroll
        for (int kk = 0; kk < 64; kk += 32) {
            short8 a = *(const short8*)&As[(w*16 + col)*64 + kk + quad*8];
            #pragma unroll
            for (int nt = 0; nt < 4; nt++) {
                short8 b = *(const short8*)&Bs[(nt*16 + col)*64 + kk + quad*8];
                acc[nt] = __builtin_amdgcn_mfma_f32_16x16x32_bf16(a, b, acc[nt], 0, 0, 0);
            }
        }
        __syncthreads();
    }
    #pragma unroll
    for (int nt = 0; nt < 4; nt++) {
        int n = n0 + nt*16 + col;
        #pragma unroll
        for (int r = 0; r < 4; r++) {
            int m = m0 + w*16 + quad*4 + r;
            out[(size_t)m*E_ + n] = acc[nt][r];
        }
    }
}

extern "C" void kernel_launch(void* const* d_in, const int* in_sizes, int n_in,
                              void* d_out, int out_size, void* d_ws, size_t ws_size,
                              hipStream_t stream) {
    (void)in_sizes; (void)n_in; (void)out_size; (void)ws_size;
    const float* x     = (const float*)d_in[0];
    const float* Wq    = (const float*)d_in[1];
    const float* Wk    = (const float*)d_in[2];
    const float* Wv    = (const float*)d_in[3];
    const float* Wo    = (const float*)d_in[4];
    const float* theta = (const float*)d_in[5];
    float* out = (float*)d_out;

    // Workspace layout (bf16 elements). ctx aliases xb (xb dead after gemm_qkv).
    unsigned short* ws  = (unsigned short*)d_ws;
    unsigned short* xb  = ws;                                    // M*E        = 8388608
    unsigned short* Wb  = xb  + (size_t)M_*E_;                   // 3*E*E      = 3145728
    unsigned short* Wob = Wb  + (size_t)3*E_*E_;                 // E*E        = 1048576
    unsigned short* qb  = Wob + (size_t)E_*E_;                   // 8388608
    unsigned short* kb  = qb  + (size_t)B_*H_*S_*DK_;            // 8388608
    unsigned short* vtb = kb  + (size_t)B_*H_*S_*DK_;            // 8388608
    unsigned short* ctx = xb;                                    // alias
    // total: ~37.7M bf16 = 75.5 MB

    cvt_bf16<<<(M_*E_/4)/256, 256, 0, stream>>>(x,  xb,  M_*E_/4);
    cvt_bf16<<<(E_*E_/4)/256, 256, 0, stream>>>(Wq, Wb,              E_*E_/4);
    cvt_bf16<<<(E_*E_/4)/256, 256, 0, stream>>>(Wk, Wb + (size_t)E_*E_,   E_*E_/4);
    cvt_bf16<<<(E_*E_/4)/256, 256, 0, stream>>>(Wv, Wb + (size_t)2*E_*E_, E_*E_/4);
    cvt_bf16<<<(E_*E_/4)/256, 256, 0, stream>>>(Wo, Wob,             E_*E_/4);

    gemm_qkv<<<dim3(M_/64, E_/64, 3), 256, 0, stream>>>(xb, Wb, theta, qb, kb, vtb);
    flash_attn<<<dim3(S_/64, B_*H_), 256, 0, stream>>>(qb, kb, vtb, ctx);
    gemm_out<<<dim3(M_/64, E_/64), 256, 0, stream>>>(ctx, Wob, out);
}

// Round 2
// 396.140 us; speedup vs baseline: 1.4748x; 1.4748x over previous
//
#include <hip/hip_runtime.h>

// Problem constants
#define B_  4
#define S_  2048
#define E_  1024
#define H_  16
#define DK_ 64
#define M_  (B_*S_)   // 8192

typedef __attribute__((ext_vector_type(8))) short short8;   // 8 bf16 (4 VGPRs)
typedef __attribute__((ext_vector_type(4))) float f32x4;    // MFMA accumulator

// fp32 -> bf16 round-to-nearest-even
__device__ __forceinline__ unsigned short f2b(float f) {
    union { float f; unsigned u; } v; v.f = f;
    unsigned u = v.u;
    return (unsigned short)((u + 0x7fffu + ((u >> 16) & 1u)) >> 16);
}

// async global->LDS, 16 bytes/lane. LDS dest = wave-uniform base + lane*16.
__device__ __forceinline__ void gload_lds16(const unsigned short* g, unsigned short* l) {
    __builtin_amdgcn_global_load_lds((const __attribute__((address_space(1))) void*)g,
                                     (__attribute__((address_space(3))) void*)l, 16, 0, 0);
}

__global__ __launch_bounds__(256) void cvt_bf16(const float* __restrict__ src,
                                                unsigned short* __restrict__ dst, int n4) {
    int i = blockIdx.x * 256 + threadIdx.x;
    if (i < n4) {
        float4 f = ((const float4*)src)[i];
        ushort4 o;
        o.x = f2b(f.x); o.y = f2b(f.y); o.z = f2b(f.z); o.w = f2b(f.w);
        ((ushort4*)dst)[i] = o;
    }
}

// ---------------------------------------------------------------------------
// 128x128-tile GEMM (m97 structure): BK=64, global_load_lds staging,
// 4 waves in 2x2, each wave 4x4 16x16x32 MFMA tiles.
// C[m][n] = sum_k A[m][k]*B[n][k]  (both row-major, K contiguous)
// ---------------------------------------------------------------------------

// y = x @ W_z.T ; q/k = cos(y + theta) -> [bh][s][d] ; v -> cos -> [bh][d][s]
__global__ __launch_bounds__(256) void gemm_qkv(
    const unsigned short* __restrict__ xb,   // [M][E]
    const unsigned short* __restrict__ Wb,   // [3][E][E]
    const float* __restrict__ theta,         // [64]
    unsigned short* __restrict__ qb,         // [B*H][S][DK]
    unsigned short* __restrict__ kb,         // [B*H][S][DK]
    unsigned short* __restrict__ vtb)        // [B*H][DK][S]
{
    __shared__ unsigned short As[128*64];    // 16 KB (unpadded: global_load_lds)
    __shared__ unsigned short Bs[128*64];
    const int tid = threadIdx.x;
    const int w = tid >> 6, lane = tid & 63, quad = lane >> 4, col = lane & 15;
    const int wm = (w & 1) * 64, wn = (w >> 1) * 64;
    const int m0 = blockIdx.x * 128, n0 = blockIdx.y * 128, z = blockIdx.z;
    const unsigned short* Wz = Wb + (size_t)z * E_ * E_;
    const int srow = lane >> 3, schunk = (lane & 7) * 8;

    f32x4 acc[4][4] = {};
    for (int k0 = 0; k0 < E_; k0 += 64) {
        #pragma unroll
        for (int c = 0; c < 4; c++) {
            int row = w*32 + c*8 + srow;
            gload_lds16(&xb[(size_t)(m0+row)*E_ + k0 + schunk], &As[(w*32 + c*8)*64]);
            gload_lds16(&Wz[(size_t)(n0+row)*E_ + k0 + schunk], &Bs[(w*32 + c*8)*64]);
        }
        __syncthreads();
        #pragma unroll
        for (int kk = 0; kk < 64; kk += 32) {
            short8 a[4], b[4];
            #pragma unroll
            for (int i = 0; i < 4; i++)
                a[i] = *(const short8*)&As[(wm + i*16 + col)*64 + kk + quad*8];
            #pragma unroll
            for (int j = 0; j < 4; j++)
                b[j] = *(const short8*)&Bs[(wn + j*16 + col)*64 + kk + quad*8];
            #pragma unroll
            for (int i = 0; i < 4; i++)
                #pragma unroll
                for (int j = 0; j < 4; j++)
                    acc[i][j] = __builtin_amdgcn_mfma_f32_16x16x32_bf16(a[i], b[j], acc[i][j], 0, 0, 0);
        }
        __syncthreads();
    }
    // Epilogue: C/D layout col=lane&15, row=quad*4+reg
    #pragma unroll
    for (int j = 0; j < 4; j++) {
        int n = n0 + wn + j*16 + col;
        int h = n >> 6, d = n & 63;
        float th = theta[d];
        #pragma unroll
        for (int i = 0; i < 4; i++) {
            #pragma unroll
            for (int r = 0; r < 4; r++) {
                int m = m0 + wm + i*16 + quad*4 + r;
                int b = m >> 11, s = m & (S_-1);
                unsigned short o = f2b(__cosf(acc[i][j][r] + th));
                int bh = b*H_ + h;
                if (z == 0)      qb [((size_t)bh*S_ + s)*DK_ + d] = o;
                else if (z == 1) kb [((size_t)bh*S_ + s)*DK_ + d] = o;
                else             vtb[((size_t)bh*DK_ + d)*S_ + s] = o;
            }
        }
    }
}

// out = ctx @ Wo.T, fp32 output
__global__ __launch_bounds__(256) void gemm_out(
    const unsigned short* __restrict__ ctx,  // [M][E]
    const unsigned short* __restrict__ Wob,  // [E][E]
    float* __restrict__ out)                 // [M][E] fp32
{
    __shared__ unsigned short As[128*64];
    __shared__ unsigned short Bs[128*64];
    const int tid = threadIdx.x;
    const int w = tid >> 6, lane = tid & 63, quad = lane >> 4, col = lane & 15;
    const int wm = (w & 1) * 64, wn = (w >> 1) * 64;
    const int m0 = blockIdx.x * 128, n0 = blockIdx.y * 128;
    const int srow = lane >> 3, schunk = (lane & 7) * 8;

    f32x4 acc[4][4] = {};
    for (int k0 = 0; k0 < E_; k0 += 64) {
        #pragma unroll
        for (int c = 0; c < 4; c++) {
            int row = w*32 + c*8 + srow;
            gload_lds16(&ctx[(size_t)(m0+row)*E_ + k0 + schunk], &As[(w*32 + c*8)*64]);
            gload_lds16(&Wob[(size_t)(n0+row)*E_ + k0 + schunk], &Bs[(w*32 + c*8)*64]);
        }
        __syncthreads();
        #pragma unroll
        for (int kk = 0; kk < 64; kk += 32) {
            short8 a[4], b[4];
            #pragma unroll
            for (int i = 0; i < 4; i++)
                a[i] = *(const short8*)&As[(wm + i*16 + col)*64 + kk + quad*8];
            #pragma unroll
            for (int j = 0; j < 4; j++)
                b[j] = *(const short8*)&Bs[(wn + j*16 + col)*64 + kk + quad*8];
            #pragma unroll
            for (int i = 0; i < 4; i++)
                #pragma unroll
                for (int j = 0; j < 4; j++)
                    acc[i][j] = __builtin_amdgcn_mfma_f32_16x16x32_bf16(a[i], b[j], acc[i][j], 0, 0, 0);
        }
        __syncthreads();
    }
    #pragma unroll
    for (int j = 0; j < 4; j++) {
        int n = n0 + wn + j*16 + col;
        #pragma unroll
        for (int i = 0; i < 4; i++)
            #pragma unroll
            for (int r = 0; r < 4; r++) {
                int m = m0 + wm + i*16 + quad*4 + r;
                out[(size_t)m*E_ + n] = acc[i][j][r];
            }
    }
}

// ---------------------------------------------------------------------------
// Flash attention, padded LDS (stride 72), fixed-max softmax.
// Scores bounded: |s| <= 64 raw (q,k in [-1,1], DK=64) -> exp(s/8) <= e^8, fp32-safe.
// ---------------------------------------------------------------------------
#define LP_ 72   // padded LDS row stride (elements); 144 B keeps 16B alignment

__global__ __launch_bounds__(256) void flash_attn(
    const unsigned short* __restrict__ qb,
    const unsigned short* __restrict__ kb,
    const unsigned short* __restrict__ vtb,
    unsigned short* __restrict__ ctx)        // [M][E] bf16
{
    __shared__ unsigned short Kt[64*LP_];    // [key][d]
    __shared__ unsigned short Vt[64*LP_];    // [d][key]
    __shared__ unsigned short Pl[4][16*LP_]; // per-wave P staging [q][key]
    const int tid = threadIdx.x;
    const int w = tid >> 6, lane = tid & 63, quad = lane >> 4, col = lane & 15;
    const int q0 = blockIdx.x * 64;
    const int bh = blockIdx.y;

    short8 qf[2];
    {
        const unsigned short* qrow = qb + ((size_t)bh*S_ + q0 + w*16 + col)*DK_;
        qf[0] = *(const short8*)&qrow[quad*8];
        qf[1] = *(const short8*)&qrow[32 + quad*8];
    }

    float l_r[4] = {0.f, 0.f, 0.f, 0.f};
    f32x4 o_acc[4] = {};

    for (int kt = 0; kt < S_; kt += 64) {
        __syncthreads();
        for (int i = tid; i < 512; i += 256) {
            int row = i >> 3, c8 = (i & 7) * 8;
            *(int4*)&Kt[row*LP_ + c8] = *(const int4*)&kb [((size_t)bh*S_  + kt + row)*DK_ + c8];
            *(int4*)&Vt[row*LP_ + c8] = *(const int4*)&vtb[((size_t)bh*DK_ + row)*S_ + kt + c8];
        }
        __syncthreads();

        // scores: S[q][key] = sum_d Q[q][d] K[key][d]  (raw, scale folded into exp)
        f32x4 sacc[4] = {};
        #pragma unroll
        for (int kk = 0; kk < 2; kk++) {
            #pragma unroll
            for (int ct = 0; ct < 4; ct++) {
                short8 bf = *(const short8*)&Kt[(ct*16 + col)*LP_ + kk*32 + quad*8];
                sacc[ct] = __builtin_amdgcn_mfma_f32_16x16x32_bf16(qf[kk], bf, sacc[ct], 0, 0, 0);
            }
        }

        // fixed-max softmax: p = exp(s/8), no running max needed
        float rsum[4] = {0.f, 0.f, 0.f, 0.f};
        #pragma unroll
        for (int ct = 0; ct < 4; ct++) {
            #pragma unroll
            for (int r = 0; r < 4; r++) {
                float p = __expf(sacc[ct][r] * 0.125f);
                rsum[r] += p;
                Pl[w][(quad*4 + r)*LP_ + ct*16 + col] = f2b(p);  // C-layout -> [q][key]
            }
        }
        #pragma unroll
        for (int r = 0; r < 4; r++) {
            float t = rsum[r];
            #pragma unroll
            for (int off = 8; off >= 1; off >>= 1)
                t += __shfl_xor(t, off, 16);
            l_r[r] += t;
        }

        // PV: O[q][d] += sum_key P[q][key] V[key][d]
        #pragma unroll
        for (int kk = 0; kk < 2; kk++) {
            short8 pa = *(const short8*)&Pl[w][col*LP_ + kk*32 + quad*8];   // A-layout
            #pragma unroll
            for (int dt = 0; dt < 4; dt++) {
                short8 bv = *(const short8*)&Vt[(dt*16 + col)*LP_ + kk*32 + quad*8];
                o_acc[dt] = __builtin_amdgcn_mfma_f32_16x16x32_bf16(pa, bv, o_acc[dt], 0, 0, 0);
            }
        }
    }

    // epilogue: normalize, write ctx [b*S+s][h*64+d]
    const int b = bh >> 4, h = bh & 15;
    #pragma unroll
    for (int r = 0; r < 4; r++) {
        float inv = 1.0f / l_r[r];
        int s = q0 + w*16 + quad*4 + r;
        size_t rowoff = ((size_t)(b*S_ + s))*E_ + h*64;
        #pragma unroll
        for (int dt = 0; dt < 4; dt++)
            ctx[rowoff + dt*16 + col] = f2b(o_acc[dt][r] * inv);
    }
}

extern "C" void kernel_launch(void* const* d_in, const int* in_sizes, int n_in,
                              void* d_out, int out_size, void* d_ws, size_t ws_size,
                              hipStream_t stream) {
    (void)in_sizes; (void)n_in; (void)out_size; (void)ws_size;
    const float* x     = (const float*)d_in[0];
    const float* Wq    = (const float*)d_in[1];
    const float* Wk    = (const float*)d_in[2];
    const float* Wv    = (const float*)d_in[3];
    const float* Wo    = (const float*)d_in[4];
    const float* theta = (const float*)d_in[5];
    float* out = (float*)d_out;

    unsigned short* ws  = (unsigned short*)d_ws;
    unsigned short* xb  = ws;                                    // M*E
    unsigned short* Wb  = xb  + (size_t)M_*E_;                   // 3*E*E
    unsigned short* Wob = Wb  + (size_t)3*E_*E_;                 // E*E
    unsigned short* qb  = Wob + (size_t)E_*E_;
    unsigned short* kb  = qb  + (size_t)B_*H_*S_*DK_;
    unsigned short* vtb = kb  + (size_t)B_*H_*S_*DK_;
    unsigned short* ctx = xb;                                    // alias (xb dead after gemm_qkv)

    cvt_bf16<<<(M_*E_/4)/256, 256, 0, stream>>>(x,  xb,  M_*E_/4);
    cvt_bf16<<<(E_*E_/4)/256, 256, 0, stream>>>(Wq, Wb,              E_*E_/4);
    cvt_bf16<<<(E_*E_/4)/256, 256, 0, stream>>>(Wk, Wb + (size_t)E_*E_,   E_*E_/4);
    cvt_bf16<<<(E_*E_/4)/256, 256, 0, stream>>>(Wv, Wb + (size_t)2*E_*E_, E_*E_/4);
    cvt_bf16<<<(E_*E_/4)/256, 256, 0, stream>>>(Wo, Wob,             E_*E_/4);

    gemm_qkv<<<dim3(M_/128, E_/128, 3), 256, 0, stream>>>(xb, Wb, theta, qb, kb, vtb);
    flash_attn<<<dim3(S_/64, B_*H_), 256, 0, stream>>>(qb, kb, vtb, ctx);
    gemm_out<<<dim3(M_/128, E_/128), 256, 0, stream>>>(ctx, Wob, out);
}

// Round 3
// 319.160 us; speedup vs baseline: 1.8305x; 1.2412x over previous
//
#include <hip/hip_runtime.h>

// Problem constants
#define B_  4
#define S_  2048
#define E_  1024
#define H_  16
#define DK_ 64
#define M_  (B_*S_)   // 8192

typedef __attribute__((ext_vector_type(8)))  short short8;   // 8 bf16 (4 VGPRs)
typedef __attribute__((ext_vector_type(4)))  float f32x4;
typedef __attribute__((ext_vector_type(16))) float f32x16;   // 32x32 MFMA accumulator

// fp32 -> bf16 round-to-nearest-even
__device__ __forceinline__ unsigned short f2b(float f) {
    union { float f; unsigned u; } v; v.f = f;
    unsigned u = v.u;
    return (unsigned short)((u + 0x7fffu + ((u >> 16) & 1u)) >> 16);
}

// async global->LDS, 16 bytes/lane. LDS dest = wave-uniform base + lane*16.
__device__ __forceinline__ void gload_lds16(const unsigned short* g, unsigned short* l) {
    __builtin_amdgcn_global_load_lds((const __attribute__((address_space(1))) void*)g,
                                     (__attribute__((address_space(3))) void*)l, 16, 0, 0);
}

__global__ __launch_bounds__(256) void cvt_bf16(const float* __restrict__ src,
                                                unsigned short* __restrict__ dst, int n4) {
    int i = blockIdx.x * 256 + threadIdx.x;
    if (i < n4) {
        float4 f = ((const float4*)src)[i];
        ushort4 o;
        o.x = f2b(f.x); o.y = f2b(f.y); o.z = f2b(f.z); o.w = f2b(f.w);
        ((ushort4*)dst)[i] = o;
    }
}

// ---------------------------------------------------------------------------
// 128x128-tile GEMM (m97 structure). For z=2 (V) the epilogue transposes the
// output tile through LDS so the vtb[bh][d][s] store is coalesced b128 rows.
// ---------------------------------------------------------------------------
__global__ __launch_bounds__(256) void gemm_qkv(
    const unsigned short* __restrict__ xb,   // [M][E]
    const unsigned short* __restrict__ Wb,   // [3][E][E]
    const float* __restrict__ theta,         // [64]
    unsigned short* __restrict__ qb,         // [B*H][S][DK]
    unsigned short* __restrict__ kb,         // [B*H][S][DK]
    unsigned short* __restrict__ vtb)        // [B*H][DK][S]
{
    __shared__ unsigned short smem[128*136];            // 34816 B
    unsigned short* As = smem;                          // [128][64]
    unsigned short* Bs = smem + 128*64;
    const int tid = threadIdx.x;
    const int w = tid >> 6, lane = tid & 63, quad = lane >> 4, col = lane & 15;
    const int wm = (w & 1) * 64, wn = (w >> 1) * 64;
    const int m0 = blockIdx.x * 128, n0 = blockIdx.y * 128, z = blockIdx.z;
    const unsigned short* Wz = Wb + (size_t)z * E_ * E_;
    const int srow = lane >> 3, schunk = (lane & 7) * 8;

    f32x4 acc[4][4] = {};
    for (int k0 = 0; k0 < E_; k0 += 64) {
        #pragma unroll
        for (int c = 0; c < 4; c++) {
            int row = w*32 + c*8 + srow;
            gload_lds16(&xb[(size_t)(m0+row)*E_ + k0 + schunk], &As[(w*32 + c*8)*64]);
            gload_lds16(&Wz[(size_t)(n0+row)*E_ + k0 + schunk], &Bs[(w*32 + c*8)*64]);
        }
        __syncthreads();
        #pragma unroll
        for (int kk = 0; kk < 64; kk += 32) {
            short8 a[4], b[4];
            #pragma unroll
            for (int i = 0; i < 4; i++)
                a[i] = *(const short8*)&As[(wm + i*16 + col)*64 + kk + quad*8];
            #pragma unroll
            for (int j = 0; j < 4; j++)
                b[j] = *(const short8*)&Bs[(wn + j*16 + col)*64 + kk + quad*8];
            #pragma unroll
            for (int i = 0; i < 4; i++)
                #pragma unroll
                for (int j = 0; j < 4; j++)
                    acc[i][j] = __builtin_amdgcn_mfma_f32_16x16x32_bf16(a[i], b[j], acc[i][j], 0, 0, 0);
        }
        __syncthreads();
    }

    const int bblk = m0 >> 11;            // batch index (128-tile never crosses S)
    const int sbase = m0 & (S_-1);

    if (z != 2) {
        // q/k: direct scatter (16-lane contiguous 32B segments)
        #pragma unroll
        for (int j = 0; j < 4; j++) {
            int n = n0 + wn + j*16 + col;
            int h = n >> 6, d = n & 63;
            float th = theta[d];
            #pragma unroll
            for (int i = 0; i < 4; i++)
                #pragma unroll
                for (int r = 0; r < 4; r++) {
                    int m = m0 + wm + i*16 + quad*4 + r;
                    int s = m & (S_-1);
                    unsigned short o = f2b(__cosf(acc[i][j][r] + th));
                    int bh = bblk*H_ + h;
                    if (z == 0) qb[((size_t)bh*S_ + s)*DK_ + d] = o;
                    else        kb[((size_t)bh*S_ + s)*DK_ + d] = o;
                }
        }
    } else {
        // V: transpose tile through LDS (smem dead after K-loop) -> coalesced store
        #pragma unroll
        for (int j = 0; j < 4; j++) {
            int nl = wn + j*16 + col;
            float th = theta[(n0 + nl) & 63];
            #pragma unroll
            for (int i = 0; i < 4; i++)
                #pragma unroll
                for (int r = 0; r < 4; r++)
                    smem[nl*136 + wm + i*16 + quad*4 + r] = f2b(__cosf(acc[i][j][r] + th));
        }
        __syncthreads();
        int row = tid >> 1, halfm = (tid & 1) * 64;     // 2 threads per n-row
        int n = n0 + row, h = n >> 6, d = n & 63;
        size_t base = ((size_t)(bblk*H_ + h)*DK_ + d)*S_ + sbase + halfm;
        #pragma unroll
        for (int k = 0; k < 8; k++)
            *(int4*)&vtb[base + k*8] = *(const int4*)&smem[row*136 + halfm + k*8];
    }
}

// out = ctx @ Wo.T, fp32 output
__global__ __launch_bounds__(256) void gemm_out(
    const unsigned short* __restrict__ ctx,  // [M][E]
    const unsigned short* __restrict__ Wob,  // [E][E]
    float* __restrict__ out)                 // [M][E] fp32
{
    __shared__ unsigned short As[128*64];
    __shared__ unsigned short Bs[128*64];
    const int tid = threadIdx.x;
    const int w = tid >> 6, lane = tid & 63, quad = lane >> 4, col = lane & 15;
    const int wm = (w & 1) * 64, wn = (w >> 1) * 64;
    const int m0 = blockIdx.x * 128, n0 = blockIdx.y * 128;
    const int srow = lane >> 3, schunk = (lane & 7) * 8;

    f32x4 acc[4][4] = {};
    for (int k0 = 0; k0 < E_; k0 += 64) {
        #pragma unroll
        for (int c = 0; c < 4; c++) {
            int row = w*32 + c*8 + srow;
            gload_lds16(&ctx[(size_t)(m0+row)*E_ + k0 + schunk], &As[(w*32 + c*8)*64]);
            gload_lds16(&Wob[(size_t)(n0+row)*E_ + k0 + schunk], &Bs[(w*32 + c*8)*64]);
        }
        __syncthreads();
        #pragma unroll
        for (int kk = 0; kk < 64; kk += 32) {
            short8 a[4], b[4];
            #pragma unroll
            for (int i = 0; i < 4; i++)
                a[i] = *(const short8*)&As[(wm + i*16 + col)*64 + kk + quad*8];
            #pragma unroll
            for (int j = 0; j < 4; j++)
                b[j] = *(const short8*)&Bs[(wn + j*16 + col)*64 + kk + quad*8];
            #pragma unroll
            for (int i = 0; i < 4; i++)
                #pragma unroll
                for (int j = 0; j < 4; j++)
                    acc[i][j] = __builtin_amdgcn_mfma_f32_16x16x32_bf16(a[i], b[j], acc[i][j], 0, 0, 0);
        }
        __syncthreads();
    }
    #pragma unroll
    for (int j = 0; j < 4; j++) {
        int n = n0 + wn + j*16 + col;
        #pragma unroll
        for (int i = 0; i < 4; i++)
            #pragma unroll
            for (int r = 0; r < 4; r++) {
                int m = m0 + wm + i*16 + quad*4 + r;
                out[(size_t)m*E_ + n] = acc[i][j][r];
            }
    }
}

// ---------------------------------------------------------------------------
// Flash attention, S^T formulation with 32x32x16 MFMA.
// Block = 128 queries, 4 waves (32 q each). K-tile = 64 keys.
//   S^T = K.Q^T : A=K [key][d] (LDS, b128), B=Q (regs). C: col=q, row=key.
//   -> l accumulates per-lane (all of a lane's p's share one q); one shfl at end.
//   -> P packs 4 consecutive keys per reg-group -> ds_write_b64 into Pl[q][key].
//   O = P.V^T : A=P [q][key] (b128), B=Vt [d][key] (b128). C: col=d -> coalesced.
// Fixed-max softmax: |score| <= 64 raw, exp(s/8) <= e^8 (fp32-safe).
// ---------------------------------------------------------------------------
#define LPK 72   // padded LDS row stride (elements); 144 B, 16B-aligned

__global__ __launch_bounds__(256, 4) void flash_attn(
    const unsigned short* __restrict__ qb,
    const unsigned short* __restrict__ kb,
    const unsigned short* __restrict__ vtb,
    unsigned short* __restrict__ ctx)        // [M][E] bf16
{
    __shared__ unsigned short Kt[64*LPK];    // [key][d]
    __shared__ unsigned short Vt[64*LPK];    // [d][key]
    __shared__ unsigned short Pl[4*32*LPK];  // per-wave P [q][key]
    __shared__ float l_s[128];
    const int tid = threadIdx.x;
    const int w = tid >> 6, lane = tid & 63, col = lane & 31, half = lane >> 5;
    const int q0 = blockIdx.x * 128;
    const int bh = blockIdx.y;
    unsigned short* Pw = Pl + w*32*LPK;

    // Q B-frags: lane holds Q[q0+w*32+col][c*16 + half*8 + j]
    short8 qf[4];
    {
        const unsigned short* qrow = qb + ((size_t)bh*S_ + q0 + w*32 + col)*DK_;
        #pragma unroll
        for (int c = 0; c < 4; c++)
            qf[c] = *(const short8*)&qrow[c*16 + half*8];
    }

    float rsum = 0.f;
    f32x16 oacc[2] = {};

    for (int kt = 0; kt < S_; kt += 64) {
        __syncthreads();
        for (int i = tid; i < 512; i += 256) {
            int row = i >> 3, c8 = (i & 7) * 8;
            *(int4*)&Kt[row*LPK + c8] = *(const int4*)&kb [((size_t)bh*S_  + kt + row)*DK_ + c8];
            *(int4*)&Vt[row*LPK + c8] = *(const int4*)&vtb[((size_t)bh*DK_ + row)*S_ + kt + c8];
        }
        __syncthreads();

        // S^T per 32-key tile; softmax; pack P
        #pragma unroll
        for (int t = 0; t < 2; t++) {
            f32x16 sacc = {};
            #pragma unroll
            for (int c = 0; c < 4; c++) {
                short8 kf = *(const short8*)&Kt[(t*32 + col)*LPK + c*16 + half*8];
                sacc = __builtin_amdgcn_mfma_f32_32x32x16_bf16(kf, qf[c], sacc, 0, 0, 0);
            }
            #pragma unroll
            for (int rg = 0; rg < 4; rg++) {
                float p0 = __expf(sacc[rg*4+0] * 0.125f);
                float p1 = __expf(sacc[rg*4+1] * 0.125f);
                float p2 = __expf(sacc[rg*4+2] * 0.125f);
                float p3 = __expf(sacc[rg*4+3] * 0.125f);
                rsum += (p0 + p1) + (p2 + p3);
                uint2 pk;
                pk.x = (unsigned)f2b(p0) | ((unsigned)f2b(p1) << 16);
                pk.y = (unsigned)f2b(p2) | ((unsigned)f2b(p3) << 16);
                // reg rr -> key = t*32 + rg*8 + half*4 + rr  (4 consecutive)
                *(uint2*)&Pw[col*LPK + t*32 + rg*8 + half*4] = pk;
            }
        }

        // O += P . V^T
        short8 pfrag[4];
        #pragma unroll
        for (int kc = 0; kc < 4; kc++)
            pfrag[kc] = *(const short8*)&Pw[col*LPK + kc*16 + half*8];
        #pragma unroll
        for (int dt = 0; dt < 2; dt++)
            #pragma unroll
            for (int kc = 0; kc < 4; kc++) {
                short8 vf = *(const short8*)&Vt[(dt*32 + col)*LPK + kc*16 + half*8];
                oacc[dt] = __builtin_amdgcn_mfma_f32_32x32x16_bf16(pfrag[kc], vf, oacc[dt], 0, 0, 0);
            }
    }

    // l(q) lives split across the two half-wave lanes with the same col
    float l = rsum + __shfl_xor(rsum, 32);
    l_s[w*32 + col] = l;                    // both halves write the same value

    const int b = bh >> 4, h = bh & 15;
    #pragma unroll
    for (int rg = 0; rg < 4; rg++)
        #pragma unroll
        for (int rr = 0; rr < 4; rr++) {
            int row = rr + rg*8 + half*4;   // q within wave tile
            float inv = 1.0f / l_s[w*32 + row];
            int s = q0 + w*32 + row;
            size_t rowoff = ((size_t)(b*S_ + s))*E_ + h*64;
            #pragma unroll
            for (int dt = 0; dt < 2; dt++)
                ctx[rowoff + dt*32 + col] = f2b(oacc[dt][rg*4 + rr] * inv);
        }
}

extern "C" void kernel_launch(void* const* d_in, const int* in_sizes, int n_in,
                              void* d_out, int out_size, void* d_ws, size_t ws_size,
                              hipStream_t stream) {
    (void)in_sizes; (void)n_in; (void)out_size; (void)ws_size;
    const float* x     = (const float*)d_in[0];
    const float* Wq    = (const float*)d_in[1];
    const float* Wk    = (const float*)d_in[2];
    const float* Wv    = (const float*)d_in[3];
    const float* Wo    = (const float*)d_in[4];
    const float* theta = (const float*)d_in[5];
    float* out = (float*)d_out;

    unsigned short* ws  = (unsigned short*)d_ws;
    unsigned short* xb  = ws;                                    // M*E
    unsigned short* Wb  = xb  + (size_t)M_*E_;                   // 3*E*E
    unsigned short* Wob = Wb  + (size_t)3*E_*E_;                 // E*E
    unsigned short* qb  = Wob + (size_t)E_*E_;
    unsigned short* kb  = qb  + (size_t)B_*H_*S_*DK_;
    unsigned short* vtb = kb  + (size_t)B_*H_*S_*DK_;
    unsigned short* ctx = xb;                                    // alias (xb dead after gemm_qkv)

    cvt_bf16<<<(M_*E_/4)/256, 256, 0, stream>>>(x,  xb,  M_*E_/4);
    cvt_bf16<<<(E_*E_/4)/256, 256, 0, stream>>>(Wq, Wb,              E_*E_/4);
    cvt_bf16<<<(E_*E_/4)/256, 256, 0, stream>>>(Wk, Wb + (size_t)E_*E_,   E_*E_/4);
    cvt_bf16<<<(E_*E_/4)/256, 256, 0, stream>>>(Wv, Wb + (size_t)2*E_*E_, E_*E_/4);
    cvt_bf16<<<(E_*E_/4)/256, 256, 0, stream>>>(Wo, Wob,             E_*E_/4);

    gemm_qkv<<<dim3(M_/128, E_/128, 3), 256, 0, stream>>>(xb, Wb, theta, qb, kb, vtb);
    flash_attn<<<dim3(S_/128, B_*H_), 256, 0, stream>>>(qb, kb, vtb, ctx);
    gemm_out<<<dim3(M_/128, E_/128), 256, 0, stream>>>(ctx, Wob, out);
}